// Round 2
// baseline (187.319 us; speedup 1.0000x reference)
//
#include <hip/hip_runtime.h>

#define TT 1024
#define LL 32
#define CHUNK 4
#define NBLK (TT/CHUNK)   // 256 blocks

// d_ws layout (floats):
#define ALPHA0_OFF 0                       // 32: alpha0 = Ms[0][BEG][:]
#define PATH_OFF   32                      // 256: per-block path partials
#define P0_OFF     288                     // 256 chunk-product matrices (1024 each)
#define P1_OFF     (P0_OFF + NBLK*1024)    // 16 matrices

#define LDP (LL + 1)

// One lse-semiring matmul step with A in registers:
// thread owns C[i][j]=a; row i of A lives in this thread's 32-lane group.
// Bcol points at &B[0][j] (LDS), stride LDP.
__device__ __forceinline__ float lse_mul_step(float a, const float* Bcol) {
  float s[LL];
  #pragma unroll
  for (int k = 0; k < LL; k++) s[k] = __shfl(a, k, 32) + Bcol[k * LDP];
  // pairwise max tree (depth 5)
  float t[LL];
  #pragma unroll
  for (int k = 0; k < LL; k++) t[k] = s[k];
  #pragma unroll
  for (int st = 16; st >= 1; st >>= 1) {
    #pragma unroll
    for (int k = 0; k < st; k++) t[k] = fmaxf(t[k], t[k + st]);
  }
  const float mx = t[0];
  float a0 = 0.f, a1 = 0.f, a2 = 0.f, a3 = 0.f;
  float a4 = 0.f, a5 = 0.f, a6 = 0.f, a7 = 0.f;
  #pragma unroll
  for (int k = 0; k < LL; k += 8) {
    a0 += __expf(s[k]     - mx);
    a1 += __expf(s[k + 1] - mx);
    a2 += __expf(s[k + 2] - mx);
    a3 += __expf(s[k + 3] - mx);
    a4 += __expf(s[k + 4] - mx);
    a5 += __expf(s[k + 5] - mx);
    a6 += __expf(s[k + 6] - mx);
    a7 += __expf(s[k + 7] - mx);
  }
  const float sum = ((a0 + a1) + (a2 + a3)) + ((a4 + a5) + (a6 + a7));
  return mx + __logf(sum);
}

// Stage A: each block streams CHUNK t-slices of X, builds Ms in LDS,
// emits path partial + alpha0, and the lse-product of its chunk.
__global__ __launch_bounds__(1024, 1) void crf_stageA(
    const float4* __restrict__ X4, const float* __restrict__ w,
    const int* __restrict__ label, float* __restrict__ ws) {
  __shared__ float Ms[CHUNK][LL][LDP];
  const int blk = blockIdx.x, tid = threadIdx.x;
  const int l5 = tid & 31;        // lane over K (float4 covers 4 k's)
  const int grp = tid >> 5;       // 0..31: output cell slot (cell%32)
  const float4 w4 = reinterpret_cast<const float4*>(w)[l5];
  const size_t base = (size_t)blk * CHUNK * 1024u * 32u;

  #pragma unroll 8
  for (int q = 0; q < CHUNK * LL; q++) {
    const int m = q >> 5, it = q & 31;
    float4 xv = X4[base + (size_t)(m * 1024 + it * 32 + grp) * 32u + l5];
    float v = fmaf(xv.x, w4.x, fmaf(xv.y, w4.y, fmaf(xv.z, w4.z, xv.w * w4.w)));
    v += __shfl_xor(v, 16, 32);
    v += __shfl_xor(v,  8, 32);
    v += __shfl_xor(v,  4, 32);
    v += __shfl_xor(v,  2, 32);
    v += __shfl_xor(v,  1, 32);
    if (l5 == 0) Ms[m][it][grp] = v;
  }
  __syncthreads();

  if (tid == 0) {
    float ps = 0.f;
    const int t0 = blk * CHUNK;
    for (int m = 0; m < CHUNK; m++) {
      const int t = t0 + m;
      const int lab = label[t];
      const int pv = (t == 0) ? 0 : label[t - 1];   // BEG = 0
      ps += Ms[m][pv][lab];
    }
    ws[PATH_OFF + blk] = ps;
  }
  if (blk == 0 && tid < LL) ws[ALPHA0_OFF + tid] = Ms[0][0][tid];

  // chunk product, A in registers, no barriers (Ms read-only from here)
  const int i = grp, j = l5;
  const int first = (blk == 0) ? 1 : 0;   // Ms[0] feeds alpha0, not the product
  float a = Ms[first][i][j];
  for (int m = first + 1; m < CHUNK; m++)
    a = lse_mul_step(a, &Ms[m][0][j]);
  ws[P0_OFF + blk * 1024 + tid] = a;
}

// Radix-16 combine: block b multiplies src[16b..16b+15] in order -> dst[b].
__global__ __launch_bounds__(1024, 1) void crf_combine16(
    const float* __restrict__ src, float* __restrict__ dst) {
  __shared__ float Bm[2][LL][LDP];
  const int blk = blockIdx.x, tid = threadIdx.x;
  const int i = tid >> 5, j = tid & 31;
  const float* sp = src + (size_t)blk * 16 * 1024;
  float a = sp[tid];
  for (int r = 1; r < 16; r++) {
    Bm[r & 1][i][j] = sp[r * 1024 + tid];
    __syncthreads();                 // B visible; also fences r-2's reads
    a = lse_mul_step(a, &Bm[r & 1][0][j]);
  }
  dst[(size_t)blk * 1024 + tid] = a;
}

// Final: radix-16 product of P1, then logZ = lse(alpha0[i]+P[i][j]) and
// path-score sum; out = -path + logZ.
__global__ __launch_bounds__(1024, 1) void crf_final16(
    const float* __restrict__ ws, float* __restrict__ out) {
  __shared__ float Bm[2][LL][LDP];
  __shared__ float redm[16], reds[16], redp[16];
  const int tid = threadIdx.x;
  const int i = tid >> 5, j = tid & 31;
  const float* sp = ws + P1_OFF;
  float a = sp[tid];
  for (int r = 1; r < 16; r++) {
    Bm[r & 1][i][j] = sp[r * 1024 + tid];
    __syncthreads();
    a = lse_mul_step(a, &Bm[r & 1][0][j]);
  }
  // global lse over v = alpha0[i] + P[i][j]
  const float v = ws[ALPHA0_OFF + i] + a;
  float m = v;
  #pragma unroll
  for (int o = 32; o >= 1; o >>= 1) m = fmaxf(m, __shfl_xor(m, o));
  const int wid = tid >> 6, lane = tid & 63;
  if (lane == 0) redm[wid] = m;
  __syncthreads();
  float mb = redm[0];
  #pragma unroll
  for (int q = 1; q < 16; q++) mb = fmaxf(mb, redm[q]);
  float e = __expf(v - mb);
  float p = (tid < 256) ? ws[PATH_OFF + tid] : 0.f;
  #pragma unroll
  for (int o = 32; o >= 1; o >>= 1) {
    e += __shfl_xor(e, o);
    p += __shfl_xor(p, o);
  }
  if (lane == 0) { reds[wid] = e; redp[wid] = p; }
  __syncthreads();
  if (tid == 0) {
    float s = 0.f, ps = 0.f;
    for (int q = 0; q < 16; q++) { s += reds[q]; ps += redp[q]; }
    out[0] = -ps + (mb + __logf(s));
  }
}

extern "C" void kernel_launch(void* const* d_in, const int* in_sizes, int n_in,
                              void* d_out, int out_size, void* d_ws, size_t ws_size,
                              hipStream_t stream) {
  const float4* X4 = (const float4*)d_in[0];
  const float* w = (const float*)d_in[1];
  const int* label = (const int*)d_in[2];
  float* out = (float*)d_out;
  float* ws = (float*)d_ws;

  crf_stageA<<<NBLK, 1024, 0, stream>>>(X4, w, label, ws);
  crf_combine16<<<16, 1024, 0, stream>>>(ws + P0_OFF, ws + P1_OFF);
  crf_final16<<<1, 1024, 0, stream>>>(ws, out);
}

// Round 3
// 164.856 us; speedup vs baseline: 1.1363x; 1.1363x over previous
//
#include <hip/hip_runtime.h>

#define TT 1024
#define LL 32
#define LDP (LL + 1)
#define CHUNK 4
#define NBLK (TT / CHUNK)   // 256 blocks

// d_ws float offsets
#define ALPHA0_OFF 0                        // 32 floats
#define PATH_OFF   32                       // 256 floats
#define P0_OFF     288                      // 256 matrices x 1024
#define P1_OFF     (P0_OFF + 256 * 1024)    // 64 matrices
#define P2_OFF     (P1_OFF + 64 * 1024)     // 16 matrices
#define P3_OFF     (P2_OFF + 16 * 1024)     // 4 matrices
#define CNT_OFF    (P3_OFF + 4 * 1024)      // 85 ints (64+16+4+1)

// lse-semiring matmul step, A row in this thread's 32-lane group (register a),
// B column j in LDS at Bcol with stride LDP. Register-lean: t[16] max tree.
__device__ __forceinline__ float lse_mul_step(float a, const float* Bcol) {
  float s[LL];
  #pragma unroll
  for (int k = 0; k < LL; k++) s[k] = __shfl(a, k, 32) + Bcol[k * LDP];
  float t[16];
  #pragma unroll
  for (int k = 0; k < 16; k++) t[k] = fmaxf(s[k], s[k + 16]);
  #pragma unroll
  for (int st = 8; st >= 1; st >>= 1) {
    #pragma unroll
    for (int k = 0; k < st; k++) t[k] = fmaxf(t[k], t[k + st]);
  }
  const float mx = t[0];
  float a0 = 0.f, a1 = 0.f, a2 = 0.f, a3 = 0.f;
  #pragma unroll
  for (int k = 0; k < LL; k += 4) {
    a0 += __expf(s[k]     - mx);
    a1 += __expf(s[k + 1] - mx);
    a2 += __expf(s[k + 2] - mx);
    a3 += __expf(s[k + 3] - mx);
  }
  return mx + __logf((a0 + a1) + (a2 + a3));
}

__global__ __launch_bounds__(1024, 1) void crf_fused(
    const float4* __restrict__ X4, const float* __restrict__ w,
    const int* __restrict__ label, float* __restrict__ ws,
    int* __restrict__ cnt, float* __restrict__ out) {
  __shared__ float Ms[CHUNK][LL][LDP];
  __shared__ float M4[4][LL][LDP];
  __shared__ float redm[16], reds[16], redp[16];
  __shared__ int last;
  const int blk = blockIdx.x, tid = threadIdx.x;
  const int l5 = tid & 31;          // lane over K (float4 covers 4 k)
  const int grp = tid >> 5;         // 0..31: cell slot (cell % 32)
  const float4 w4 = reinterpret_cast<const float4*>(w)[l5];
  const size_t base = (size_t)blk * CHUNK * 1024u * 32u;

  // ---- stream X -> Ms (round-1 proven structure) ----
  #pragma unroll
  for (int m = 0; m < CHUNK; m++) {
    #pragma unroll 4
    for (int it = 0; it < LL; it++) {
      float4 xv = X4[base + (size_t)(m * 1024 + it * 32 + grp) * 32u + l5];
      float v = fmaf(xv.x, w4.x, fmaf(xv.y, w4.y, fmaf(xv.z, w4.z, xv.w * w4.w)));
      v += __shfl_xor(v, 16, 32);
      v += __shfl_xor(v,  8, 32);
      v += __shfl_xor(v,  4, 32);
      v += __shfl_xor(v,  2, 32);
      v += __shfl_xor(v,  1, 32);
      if (l5 == 0) Ms[m][it][grp] = v;
    }
  }
  __syncthreads();

  // ---- path partial + alpha0 ----
  if (tid == 0) {
    float ps = 0.f;
    const int t0 = blk * CHUNK;
    for (int m = 0; m < CHUNK; m++) {
      const int t = t0 + m;
      const int lab = label[t];
      const int pv = (t == 0) ? 0 : label[t - 1];   // BEG = 0
      ps += Ms[m][pv][lab];
    }
    ws[PATH_OFF + blk] = ps;
  }
  if (blk == 0 && tid < LL) ws[ALPHA0_OFF + tid] = Ms[0][0][tid];

  // ---- in-block chunk product (Ms read-only, no barriers) ----
  const int i2 = tid >> 5, j2 = tid & 31;
  const int first = (blk == 0) ? 1 : 0;   // Ms[0] feeds alpha0, not the product
  float a = Ms[first][i2][j2];
  #pragma unroll
  for (int m = 1; m < CHUNK; m++)
    if (m > first) a = lse_mul_step(a, &Ms[m][0][j2]);

  // ---- fused radix-4 tree: last arriver of each group continues ----
  const int POFF[4] = {P0_OFF, P1_OFF, P2_OFF, P3_OFF};
  const int CB[4]   = {0, 64, 80, 84};
  int idx = blk;
  for (int lvl = 0; lvl < 4; lvl++) {
    ws[POFF[lvl] + (size_t)idx * 1024 + tid] = a;
    __syncthreads();                    // all block stores drained (vmcnt 0)
    if (tid == 0) {
      __threadfence();                  // L2 writeback -> device-visible
      last = atomicAdd(&cnt[CB[lvl] + (idx >> 2)], 1);
    }
    __syncthreads();
    if (last != 3) return;              // uniform: not the last arriver
    if (tid == 0) __threadfence();      // invalidate stale caches before reads
    __syncthreads();
    const int g = idx >> 2;
    const float* sp = ws + POFF[lvl] + (size_t)g * 4 * 1024;
    #pragma unroll
    for (int r = 0; r < 4; r++) M4[r][i2][j2] = sp[(size_t)r * 1024 + tid];
    __syncthreads();
    a = M4[0][i2][j2];
    #pragma unroll
    for (int r = 1; r < 4; r++) a = lse_mul_step(a, &M4[r][0][j2]);
    idx = g;
  }

  // ---- final block: logZ = lse over alpha0[i]+P[i][j]; path sum; output ----
  const float v = ws[ALPHA0_OFF + i2] + a;
  float mx = v;
  #pragma unroll
  for (int o = 32; o >= 1; o >>= 1) mx = fmaxf(mx, __shfl_xor(mx, o));
  const int wid = tid >> 6, lane = tid & 63;
  if (lane == 0) redm[wid] = mx;
  __syncthreads();
  float mb = redm[0];
  #pragma unroll
  for (int q = 1; q < 16; q++) mb = fmaxf(mb, redm[q]);
  float e = __expf(v - mb);
  float p = (tid < 256) ? ws[PATH_OFF + tid] : 0.f;
  #pragma unroll
  for (int o = 32; o >= 1; o >>= 1) {
    e += __shfl_xor(e, o);
    p += __shfl_xor(p, o);
  }
  if (lane == 0) { reds[wid] = e; redp[wid] = p; }
  __syncthreads();
  if (tid == 0) {
    float s = 0.f, ps = 0.f;
    for (int q = 0; q < 16; q++) { s += reds[q]; ps += redp[q]; }
    out[0] = -ps + (mb + __logf(s));
  }
}

extern "C" void kernel_launch(void* const* d_in, const int* in_sizes, int n_in,
                              void* d_out, int out_size, void* d_ws, size_t ws_size,
                              hipStream_t stream) {
  const float4* X4 = (const float4*)d_in[0];
  const float* w = (const float*)d_in[1];
  const int* label = (const int*)d_in[2];
  float* out = (float*)d_out;
  float* ws = (float*)d_ws;
  int* cnt = (int*)(ws + CNT_OFF);

  hipMemsetAsync(cnt, 0, 85 * sizeof(int), stream);
  crf_fused<<<NBLK, 1024, 0, stream>>>(X4, w, label, ws, cnt, out);
}